// Round 7
// baseline (33.233 us; speedup 1.0000x reference)
//
#include <hip/hip_runtime.h>
#include <hip/hip_bf16.h>

#define TD 512
#define SD 128
#define NT 8
#define BATCH 16384

typedef float f32x4 __attribute__((ext_vector_type(4)));
typedef short s16x8 __attribute__((ext_vector_type(8)));
typedef unsigned short u16;

__device__ __forceinline__ u16 f2bf(float f) {
    return __builtin_bit_cast(u16, __float2bfloat16(f));   // RNE
}

// prep: logits output + WF (W as B-fragments in lane order, bf16).
// WF[cg][ks][lane][j] = W[ks*32 + (lane>>4)*8 + j][cg*16 + (lane&15)]
// -> main kernel B-loads are contiguous 16 B/lane (perfectly coalesced).
__global__ __launch_bounds__(256) void prep_kernel(
    const float* __restrict__ W, const float* __restrict__ clogits,
    const int* __restrict__ slot, const int* __restrict__ hit,
    u16* __restrict__ WF, float* __restrict__ logits_out)
{
    const int gid = blockIdx.x * 256 + threadIdx.x;   // 0..32767
    {   // logits: 2 threads per row, f32x4 each
        const int row = gid >> 1;
        const int j4 = (gid & 1) * 4;
        f32x4 v = (f32x4){0.f, 0.f, 0.f, 0.f};
        if (hit[row]) v = *(const f32x4*)(clogits + (long)slot[row] * NT + j4);
        *(f32x4*)(logits_out + (long)row * NT + j4) = v;
    }
    if (gid < 8192) {   // WF: 8 colgrps x 16 ks x 64 lanes x 16 B = 128 KiB
        const int lane = gid & 63;
        const int ks   = (gid >> 6) & 15;
        const int cg   = gid >> 10;
        const int n    = cg * 16 + (lane & 15);
        const int k0   = ks * 32 + (lane >> 4) * 8;
        u16 v[8];
        #pragma unroll
        for (int j = 0; j < 8; ++j) v[j] = f2bf(W[(k0 + j) * SD + n]);
        *(s16x8*)(WF + (long)gid * 8) = *(const s16x8*)v;
    }
}

// Main: 2048 blocks x 256 thr. Wave = one 16-row x 16-col tile, full K=512.
// No LDS, no barriers. B frags in 64 VGPRs (coalesced from WF, L2-hot).
// A gathered to regs, depth-2 prefetch, miss lanes exec-masked.
// XCD-contiguous tile map: the 8 col-waves of a row-group share one XCD's L2;
// a block's 4 waves share the row-group in L1.
__global__ __launch_bounds__(256, 3) void gemm_kernel(
    const float* __restrict__ emb,            // [500000][512]
    const u16* __restrict__ WF,               // [8][16][64][8] bf16
    const int* __restrict__ slot,             // [16384]
    const int* __restrict__ hit,              // [16384] int32 bool
    float* __restrict__ feats_out)            // [16384][128]
{
    const int t    = ((blockIdx.x & 7) << 8) | (blockIdx.x >> 3);  // bijective
    const int wv   = threadIdx.x >> 6;
    const int lane = threadIdx.x & 63;
    const int wg   = t * 4 + wv;              // 0..8191
    const int rowgrp = wg >> 3;
    const int colgrp = wg & 7;
    const int lr = lane & 15;                 // A row / B col / D col
    const int kb = lane >> 4;                 // k-octet
    const int m0 = rowgrp * 16;
    const int c0 = colgrp * 16;

    const int arow = m0 + lr;
    const int hitv = hit[arow];
    const float* ap = emb + (long)slot[arow] * TD + kb * 8;

    // ---- B fragments: 16 coalesced dwordx4 from WF ----
    s16x8 breg[16];
    #pragma unroll
    for (int ks = 0; ks < 16; ++ks)
        breg[ks] = *(const s16x8*)(WF + (((long)colgrp * 16 + ks) * 64 + lane) * 8);

    f32x4 acc = (f32x4){0.f, 0.f, 0.f, 0.f};
    f32x4 af[2][8];

    if (hitv) {   // prefetch k-group 0
        #pragma unroll
        for (int k2 = 0; k2 < 4; ++k2) {
            af[0][2 * k2]     = *(const f32x4*)(ap + k2 * 32);
            af[0][2 * k2 + 1] = *(const f32x4*)(ap + k2 * 32 + 4);
        }
    }

    #pragma unroll
    for (int g = 0; g < 4; ++g) {             // fully unrolled: static af idx
        const int cur = g & 1, nxt = cur ^ 1;
        if (g < 3 && hitv) {
            #pragma unroll
            for (int k2 = 0; k2 < 4; ++k2) {
                af[nxt][2 * k2]     = *(const f32x4*)(ap + (g + 1) * 128 + k2 * 32);
                af[nxt][2 * k2 + 1] = *(const f32x4*)(ap + (g + 1) * 128 + k2 * 32 + 4);
            }
        }
        #pragma unroll
        for (int k2 = 0; k2 < 4; ++k2) {
            s16x8 a;
            if (hitv) {
                const f32x4 f0 = af[cur][2 * k2], f1 = af[cur][2 * k2 + 1];
                #pragma unroll
                for (int j = 0; j < 4; ++j) a[j]     = (short)f2bf(f0[j]);
                #pragma unroll
                for (int j = 0; j < 4; ++j) a[4 + j] = (short)f2bf(f1[j]);
            } else {
                a = (s16x8){0, 0, 0, 0, 0, 0, 0, 0};
            }
            acc = __builtin_amdgcn_mfma_f32_16x16x32_bf16(a, breg[g * 4 + k2],
                                                          acc, 0, 0, 0);
        }
    }

    // ---- store 16x16 tile: D row = kb*4+i, col = c0+lr ----
    #pragma unroll
    for (int i = 0; i < 4; ++i)
        feats_out[(long)(m0 + kb * 4 + i) * SD + c0 + lr] = acc[i];
}

extern "C" void kernel_launch(void* const* d_in, const int* in_sizes, int n_in,
                              void* d_out, int out_size, void* d_ws, size_t ws_size,
                              hipStream_t stream) {
    const float* cache_emb    = (const float*)d_in[0];
    const float* cache_logits = (const float*)d_in[1];
    const float* W            = (const float*)d_in[2];
    const int*   slot_idx     = (const int*)d_in[3];
    const int*   hitm         = (const int*)d_in[4];

    float* feats_out  = (float*)d_out;                       // 16384*128
    float* logits_out = (float*)d_out + (long)BATCH * SD;    // 16384*8

    u16* WF = (u16*)d_ws;                                    // 128 KiB

    prep_kernel<<<128, 256, 0, stream>>>(W, cache_logits, slot_idx, hitm,
                                         WF, logits_out);
    gemm_kernel<<<2048, 256, 0, stream>>>(cache_emb, WF, slot_idx, hitm,
                                          feats_out);
}

// Round 8
// 19.777 us; speedup vs baseline: 1.6803x; 1.6803x over previous
//
#include <hip/hip_runtime.h>
#include <hip/hip_bf16.h>

#define TD 512
#define SD 128
#define NT 8
#define BATCH 16384
#define BR 32              // rows per block

typedef float f32x4 __attribute__((ext_vector_type(4)));
typedef short s16x8 __attribute__((ext_vector_type(8)));
typedef unsigned short u16;
typedef unsigned long long u64;

__device__ __forceinline__ u16 f2bf(float f) {
    return __builtin_bit_cast(u16, __float2bfloat16(f));   // RNE
}
__device__ __forceinline__ u64 pack4bf(f32x4 v) {
    u16 a[4];
    #pragma unroll
    for (int j = 0; j < 4; ++j) a[j] = f2bf(v[j]);
    return __builtin_bit_cast(u64, *(ushort4*)a);
}

// prep: WF = W as MFMA B-fragments in lane order (bf16).
// WF[(cg*16 + kidx)*64 + lane][j] = W[kidx*32 + (lane>>4)*8 + j][cg*16 + (lane&15)]
__global__ __launch_bounds__(256) void prep_kernel(
    const float* __restrict__ W, u16* __restrict__ WF) {
    const int gid = blockIdx.x * 256 + threadIdx.x;   // 0..8191
    const int lane = gid & 63;
    const int kidx = (gid >> 6) & 15;
    const int cg   = gid >> 10;
    const int n    = cg * 16 + (lane & 15);
    const int k0   = kidx * 32 + (lane >> 4) * 8;
    u16 v[8];
    #pragma unroll
    for (int j = 0; j < 8; ++j) v[j] = f2bf(W[(k0 + j) * SD + n]);
    *(s16x8*)(WF + (long)gid * 8) = *(const s16x8*)v;
}

// Main: 512 blocks x 256 thr (4 waves). Block = 32 rows, full N, full K.
// Gather: wave-cooperative, 1 contiguous KB per instruction, uniform skip of
// miss rows. A in swizzled LDS bf16 [32][512]. B frags from WF (L2-hot,
// lane-contiguous). One barrier. Compute: wave = 16 rows x 64 cols.
__global__ __launch_bounds__(256, 2) void fused_kernel(
    const float* __restrict__ emb,            // [500000][512]
    const float* __restrict__ clogits,        // [500000][8]
    const u16* __restrict__ WF,               // [8][16][64][8] bf16
    const int* __restrict__ slot,             // [16384]
    const int* __restrict__ hit,              // [16384] int32 bool
    float* __restrict__ feats_out,            // [16384][128]
    float* __restrict__ logits_out)           // [16384][8]
{
    __shared__ __align__(16) char lds[BR * TD * 2];   // 32 KiB

    const int tid  = threadIdx.x;
    const int w    = tid >> 6;
    const int lane = tid & 63;
    const int m0b  = blockIdx.x * BR;

    // ---- logits load (issued first, stored later) ----
    const int lrow = m0b + (tid >> 3);
    const int lj   = tid & 7;
    float lv = 0.f;
    if (hit[lrow]) lv = clogits[(long)slot[lrow] * NT + lj];

    // ---- gather phase A: wave w owns rows w*8..w*8+7; 1 KB/instr ----
    f32x4 rg[8][2];
    #pragma unroll
    for (int r = 0; r < 8; ++r) {
        const int grow = m0b + w * 8 + r;
        if (hit[grow]) {                       // wave-uniform branch
            const float* rp = emb + (long)slot[grow] * TD + lane * 4;
            rg[r][0] = *(const f32x4*)rp;
            rg[r][1] = *(const f32x4*)(rp + 256);
        } else {
            rg[r][0] = (f32x4){0.f, 0.f, 0.f, 0.f};
            rg[r][1] = (f32x4){0.f, 0.f, 0.f, 0.f};
        }
    }

    // ---- logits store (gather loads stay in flight; they're newer) ----
    logits_out[(long)lrow * NT + lj] = lv;

    // ---- gather phase B: cvt + swizzled ds_write_b64 ----
    #pragma unroll
    for (int r = 0; r < 8; ++r) {
        const int rowL = w * 8 + r;
        const int swz = (rowL & 7) << 4;
        const int b0 = (rowL << 10) | (lane << 3);        // byte offset
        *(u64*)(lds + (b0 ^ swz))         = pack4bf(rg[r][0]);
        *(u64*)(lds + ((b0 + 512) ^ swz)) = pack4bf(rg[r][1]);
    }
    __syncthreads();

    // ---- compute: wave -> rows (w>>1)*16..+15, N-half w&1 ----
    const int lr16 = lane & 15;
    const int kb   = lane >> 4;
    const int lb   = (w >> 1) * 16;
    const int cgh  = w & 1;

    f32x4 acc[4];
    #pragma unroll
    for (int t = 0; t < 4; ++t) acc[t] = (f32x4){0.f, 0.f, 0.f, 0.f};

    const int arow = lb + lr16;
    const int aswz = (arow & 7) << 4;

    #pragma unroll
    for (int c = 0; c < 4; ++c) {
        s16x8 bfr[4][4];
        #pragma unroll
        for (int t = 0; t < 4; ++t)
            #pragma unroll
            for (int s = 0; s < 4; ++s)
                bfr[t][s] = *(const s16x8*)(WF +
                    ((long)(((cgh * 4 + t) * 16) + (c * 4 + s)) * 64 + lane) * 8);
        s16x8 ar[4];
        #pragma unroll
        for (int s = 0; s < 4; ++s) {
            const int bin = c * 256 + s * 64 + kb * 16;   // byte within row
            ar[s] = *(const s16x8*)(lds + (((arow << 10) | bin) ^ aswz));
        }
        #pragma unroll
        for (int s = 0; s < 4; ++s)
            #pragma unroll
            for (int t = 0; t < 4; ++t)
                acc[t] = __builtin_amdgcn_mfma_f32_16x16x32_bf16(
                             ar[s], bfr[t][s], acc[t], 0, 0, 0);
    }

    // ---- feats store: D row = kb*4+i, col = (cgh*4+t)*16 + lr16 ----
    #pragma unroll
    for (int t = 0; t < 4; ++t)
        #pragma unroll
        for (int i = 0; i < 4; ++i)
            feats_out[(long)(m0b + lb + kb * 4 + i) * SD +
                      (cgh * 4 + t) * 16 + lr16] = acc[t][i];
}

extern "C" void kernel_launch(void* const* d_in, const int* in_sizes, int n_in,
                              void* d_out, int out_size, void* d_ws, size_t ws_size,
                              hipStream_t stream) {
    const float* cache_emb    = (const float*)d_in[0];
    const float* cache_logits = (const float*)d_in[1];
    const float* W            = (const float*)d_in[2];
    const int*   slot_idx     = (const int*)d_in[3];
    const int*   hitm         = (const int*)d_in[4];

    float* feats_out  = (float*)d_out;                       // 16384*128
    float* logits_out = (float*)d_out + (long)BATCH * SD;    // 16384*8

    u16* WF = (u16*)d_ws;                                    // 128 KiB

    prep_kernel<<<32, 256, 0, stream>>>(W, WF);
    fused_kernel<<<BATCH / BR, 256, 0, stream>>>(cache_emb, cache_logits, WF,
                                                 slot_idx, hitm,
                                                 feats_out, logits_out);
}

// Round 9
// 14.885 us; speedup vs baseline: 2.2327x; 1.3287x over previous
//
#include <hip/hip_runtime.h>
#include <hip/hip_bf16.h>

#define TD 512
#define SD 128
#define NT 8
#define BATCH 16384
#define BR 64              // rows per block

typedef float f32x4 __attribute__((ext_vector_type(4)));
typedef short s16x8 __attribute__((ext_vector_type(8)));
typedef unsigned short u16;
typedef unsigned long long u64;

__device__ __forceinline__ u16 f2bf(float f) {
    return __builtin_bit_cast(u16, __float2bfloat16(f));   // RNE
}
__device__ __forceinline__ u64 pack4bf(f32x4 v) {
    u16 a[4];
    #pragma unroll
    for (int j = 0; j < 4; ++j) a[j] = f2bf(v[j]);
    return __builtin_bit_cast(u64, *(ushort4*)a);
}

// Single kernel. Grid 256 x 512 thr (8 waves). Block = 64 rows x 128 N x 512 K.
// LDS: A rows bf16 swizzled (64 KB) + W-fragment ping-pong buffers (2 x 32 KB).
// W staged per 128-K chunk: scalar f32 loads (L2-hot) -> pack -> conflict-free
// ds_write_b128 in MFMA-B lane order. Gather: wave-cooperative, 1 KB/instr,
// wave-uniform skip of miss rows. 4 barriers total.
__global__ __launch_bounds__(512, 2) void fused_kernel(
    const float* __restrict__ emb,            // [500000][512]
    const float* __restrict__ clogits,        // [500000][8]
    const float* __restrict__ W,              // [512][128]
    const int* __restrict__ slot,             // [16384]
    const int* __restrict__ hit,              // [16384] int32 bool
    float* __restrict__ feats_out,            // [16384][128]
    float* __restrict__ logits_out)           // [16384][8]
{
    __shared__ __align__(16) char Al[BR * TD * 2];    // 64 KiB
    __shared__ __align__(16) char Wf[2][32768];       // 64 KiB

    const int tid  = threadIdx.x;
    const int w    = tid >> 6;
    const int lane = tid & 63;
    const int m0b  = blockIdx.x * BR;

    // ---- gather: wave w owns rows w*8..w*8+7, 1 KB contiguous per instr ----
    f32x4 rg[8][2];
    #pragma unroll
    for (int r = 0; r < 8; ++r) {
        const int grow = m0b + w * 8 + r;
        if (hit[grow]) {                       // wave-uniform branch
            const float* rp = emb + (long)slot[grow] * TD + lane * 4;
            rg[r][0] = *(const f32x4*)rp;
            rg[r][1] = *(const f32x4*)(rp + 256);
        } else {
            rg[r][0] = (f32x4){0.f, 0.f, 0.f, 0.f};
            rg[r][1] = (f32x4){0.f, 0.f, 0.f, 0.f};
        }
    }

    // ---- W chunk c slot map: s = tid + 512*i -> lane=s&63, ks=(s>>6)&3,
    //      cg=(s>>8)&7; value j: W[c*128 + ks*32 + ((s>>4)&3)*8 + j][cg*16+(s&15)]
#define STAGE_LOAD(c, WS)                                                     \
    {                                                                         \
        _Pragma("unroll")                                                     \
        for (int i = 0; i < 4; ++i) {                                         \
            const int s = tid + 512 * i;                                      \
            const int kbase = (c) * 128 + ((s >> 6) & 3) * 32 +               \
                              ((s >> 4) & 3) * 8;                             \
            const int n = ((s >> 8) & 7) * 16 + (s & 15);                     \
            _Pragma("unroll")                                                 \
            for (int j = 0; j < 8; ++j)                                       \
                WS[i * 8 + j] = W[(kbase + j) * SD + n];                      \
        }                                                                     \
    }

#define STAGE_WRITE(buf, WS)                                                  \
    {                                                                         \
        _Pragma("unroll")                                                     \
        for (int i = 0; i < 4; ++i) {                                         \
            u16 v[8];                                                         \
            _Pragma("unroll")                                                 \
            for (int j = 0; j < 8; ++j) v[j] = f2bf(WS[i * 8 + j]);           \
            *(s16x8*)(Wf[buf] + (tid + 512 * i) * 16) = *(const s16x8*)v;     \
        }                                                                     \
    }

    // ---- logits (issued alongside; 1 per thread) ----
    const int lrow = m0b + (tid >> 3);
    const int lj   = tid & 7;
    float lv = 0.f;
    if (hit[lrow]) lv = clogits[(long)slot[lrow] * NT + lj];

    float wsA[32], wsB[32];
    STAGE_LOAD(0, wsA);

    // ---- A -> LDS (bf16, XOR-swizzled rows) ----
    #pragma unroll
    for (int r = 0; r < 8; ++r) {
        const int rowL = w * 8 + r;
        const int swz = (rowL & 7) << 4;
        const int b0 = (rowL << 10) | (lane << 3);
        *(u64*)(Al + (b0 ^ swz))         = pack4bf(rg[r][0]);
        *(u64*)(Al + ((b0 + 512) ^ swz)) = pack4bf(rg[r][1]);
    }
    logits_out[(long)lrow * NT + lj] = lv;

    STAGE_WRITE(0, wsA);
    STAGE_LOAD(1, wsB);

    // ---- compute identity: wave -> row-group g, N-half h ----
    const int g = w >> 1;
    const int h = w & 1;
    const int lr16 = lane & 15;
    const int kb   = lane >> 4;
    const int rowL = g * 16 + lr16;
    const int aswz = (rowL & 7) << 4;

    f32x4 acc[4];
    #pragma unroll
    for (int t = 0; t < 4; ++t) acc[t] = (f32x4){0.f, 0.f, 0.f, 0.f};

#define COMPUTE(c, buf)                                                       \
    {                                                                         \
        _Pragma("unroll")                                                     \
        for (int s4 = 0; s4 < 4; ++s4) {                                      \
            const int abyte = ((rowL << 10) |                                 \
                               ((c) * 256 + s4 * 64 + kb * 16)) ^ aswz;       \
            const s16x8 a = *(const s16x8*)(Al + abyte);                      \
            _Pragma("unroll")                                                 \
            for (int t = 0; t < 4; ++t) {                                     \
                const s16x8 b = *(const s16x8*)(Wf[buf] +                     \
                    (((h * 4 + t) * 4 + s4) * 64 + lane) * 16);               \
                acc[t] = __builtin_amdgcn_mfma_f32_16x16x32_bf16(             \
                             a, b, acc[t], 0, 0, 0);                          \
            }                                                                 \
        }                                                                     \
    }

    __syncthreads();            // bar1: A + frag c0 ready
    COMPUTE(0, 0);
    STAGE_WRITE(1, wsB);
    STAGE_LOAD(2, wsA);
    __syncthreads();            // bar2: frag c1 ready; c0 reads done
    COMPUTE(1, 1);
    STAGE_WRITE(0, wsA);        // c2 -> bufA (last read ended at bar2)
    STAGE_LOAD(3, wsB);
    __syncthreads();            // bar3: frag c2 ready; c1 reads done
    COMPUTE(2, 0);
    STAGE_WRITE(1, wsB);        // c3 -> bufB (last read ended at bar3)
    __syncthreads();            // bar4: frag c3 ready
    COMPUTE(3, 1);

#undef STAGE_LOAD
#undef STAGE_WRITE
#undef COMPUTE

    // ---- feats store: D row = kb*4+i, col = (h*4+t)*16 + lr16 ----
    #pragma unroll
    for (int t = 0; t < 4; ++t)
        #pragma unroll
        for (int i = 0; i < 4; ++i)
            feats_out[(long)(m0b + g * 16 + kb * 4 + i) * SD +
                      (h * 4 + t) * 16 + lr16] = acc[t][i];
}

extern "C" void kernel_launch(void* const* d_in, const int* in_sizes, int n_in,
                              void* d_out, int out_size, void* d_ws, size_t ws_size,
                              hipStream_t stream) {
    const float* cache_emb    = (const float*)d_in[0];
    const float* cache_logits = (const float*)d_in[1];
    const float* W            = (const float*)d_in[2];
    const int*   slot_idx     = (const int*)d_in[3];
    const int*   hitm         = (const int*)d_in[4];

    float* feats_out  = (float*)d_out;                       // 16384*128
    float* logits_out = (float*)d_out + (long)BATCH * SD;    // 16384*8

    fused_kernel<<<BATCH / BR, 512, 0, stream>>>(cache_emb, cache_logits, W,
                                                 slot_idx, hitm,
                                                 feats_out, logits_out);
}